// Round 2
// baseline (1063.788 us; speedup 1.0000x reference)
//
#include <hip/hip_runtime.h>
#include <hip/hip_bf16.h>
#include <stdint.h>

typedef __bf16 bf16_t;
typedef bf16_t bf16x8 __attribute__((ext_vector_type(8)));
typedef bf16_t bf16x4 __attribute__((ext_vector_type(4)));
typedef float  floatx4 __attribute__((ext_vector_type(4)));

constexpr int Bb = 4, Hh = 16, Nn = 2048, Dd = 64;
constexpr float SCALE = 0.125f;
constexpr float NEGF  = -3.4028234663852886e38f;   // -FLT_MAX, matches reference
constexpr size_t KELEMS = (size_t)Bb * Hh * Nn * Dd;   // 8388608

__device__ __forceinline__ uint2 bperm64(uint2 v, int byteaddr) {
    uint2 r;
    r.x = (unsigned)__builtin_amdgcn_ds_bpermute(byteaddr, (int)v.x);
    r.y = (unsigned)__builtin_amdgcn_ds_bpermute(byteaddr, (int)v.y);
    return r;
}

// ---- pre-pass 1: K fp32 -> bf16, same [b,h,key,d] layout ----
__global__ __launch_bounds__(256)
void cvt_k(const float* __restrict__ kg, bf16_t* __restrict__ kb) {
    const size_t i = ((size_t)blockIdx.x * 256 + threadIdx.x) * 8;
    float4 a = *(const float4*)(kg + i);
    float4 b = *(const float4*)(kg + i + 4);
    bf16x8 o;
    o[0]=(bf16_t)a.x; o[1]=(bf16_t)a.y; o[2]=(bf16_t)a.z; o[3]=(bf16_t)a.w;
    o[4]=(bf16_t)b.x; o[5]=(bf16_t)b.y; o[6]=(bf16_t)b.z; o[7]=(bf16_t)b.w;
    *(bf16x8*)(kb + i) = o;
}

// ---- pre-pass 2: V [b,h,key,d] fp32 -> V^T [b,h,d,key] bf16 ----
__global__ __launch_bounds__(256)
void transpose_v(const float* __restrict__ vg, bf16_t* __restrict__ vt) {
    __shared__ float tile[64][65];
    const int id = blockIdx.x;            // (b*H+h)*32 + kt
    const int bh = id >> 5, kt = id & 31;
    const int t  = threadIdx.x;
    const float* src = vg + ((size_t)bh * Nn + kt * 64) * Dd;
    {
        const int key = t >> 2, d0 = (t & 3) * 16;
        #pragma unroll
        for (int i = 0; i < 4; ++i) {
            float4 f = *(const float4*)(src + key * Dd + d0 + i * 4);
            tile[key][d0 + i*4 + 0] = f.x; tile[key][d0 + i*4 + 1] = f.y;
            tile[key][d0 + i*4 + 2] = f.z; tile[key][d0 + i*4 + 3] = f.w;
        }
    }
    __syncthreads();
    const int d = t >> 2, k0 = (t & 3) * 16;
    bf16_t* dst = vt + ((size_t)bh * Dd + d) * Nn + kt * 64 + k0;
    #pragma unroll
    for (int g = 0; g < 2; ++g) {
        bf16x8 o;
        #pragma unroll
        for (int i = 0; i < 8; ++i) o[i] = (bf16_t)tile[k0 + g*8 + i][d];
        *(bf16x8*)(dst + g * 8) = o;
    }
}

// ---- main: flash attention, S^T = K*Q^T formulation, barrier-free K-loop ----
__global__ __launch_bounds__(256, 4)
void attn_fwd(const float* __restrict__ qg,
              const bf16_t* __restrict__ kb,
              const bf16_t* __restrict__ vt,
              const void*  __restrict__ maskg,
              const float* __restrict__ biasg,
              float* __restrict__ outg)
{
    const int tid  = threadIdx.x;
    const int wave = tid >> 6;
    const int lane = tid & 63;
    const int ln   = lane & 15;   // = query col m (C-layout), = key row (K A-frag), = d row (V^T A-frag)
    const int q    = lane >> 4;   // quad

    // XCD-aware swizzle: blocks sharing a bias slice (same h,mt; b=0..3) land on
    // one XCD back-to-back; each bias byte is fetched by exactly one XCD's L2.
    const int id  = blockIdx.x;
    const int xcd = id & 7, s = id >> 3;
    const int b   = s & 3;
    const int hm  = xcd * 64 + (s >> 2);  // 0..511
    const int h   = hm >> 5;
    const int mt  = hm & 31;

    // mask dtype probe (wave-uniform)
    const int probe = ((const int*)maskg)[lane];
    const bool mask_i32 = __all(probe == 0 || probe == 1);

    const size_t head  = (size_t)(b * Hh + h) * Nn * Dd;
    const int    qbase = mt * 64 + wave * 16;
    const int    m     = qbase + ln;

    // Q B-fragments: lane&15 = m, elem e: d = q*8 + e + 32*kk  (one-time, from fp32)
    bf16x8 qf[2];
    {
        const float* qp = qg + head + (size_t)m * Dd + q * 8;
        #pragma unroll
        for (int kk = 0; kk < 2; ++kk) {
            float4 f0 = *(const float4*)(qp + kk * 32);
            float4 f1 = *(const float4*)(qp + kk * 32 + 4);
            bf16x8 t;
            t[0]=(bf16_t)f0.x; t[1]=(bf16_t)f0.y; t[2]=(bf16_t)f0.z; t[3]=(bf16_t)f0.w;
            t[4]=(bf16_t)f1.x; t[5]=(bf16_t)f1.y; t[6]=(bf16_t)f1.z; t[7]=(bf16_t)f1.w;
            qf[kk] = t;
        }
    }

    floatx4 o_acc[4];
    #pragma unroll
    for (int i = 0; i < 4; ++i) o_acc[i] = (floatx4){0.f, 0.f, 0.f, 0.f};
    float mx = -__builtin_inff(), lsum = 0.f;

    const bf16_t* kptr = kb + head + (size_t)ln * Dd + q * 8;           // + (koff+blk*16)*64 + kk*32
    const bf16_t* vptr = vt + head + (size_t)ln * Nn + q * 8;           // + nb*16*Nn + koff + kk*32
    const float*  bptr = biasg + ((size_t)h * Nn + m) * Nn + q * 4;     // + koff + blk*16
    const int*           mip = (const int*)maskg + ((size_t)b * Nn + m) * Nn + q * 4;
    const unsigned char* mbp = (const unsigned char*)maskg + ((size_t)b * Nn + m) * Nn + q * 4;

    const int lo_src = (ln | ((lane & 16) << 1)) << 2;   // bpermute byte addr
    const int hi_src = lo_src + (16 << 2);
    const bool hiSel = (lane >= 32);

    for (int kt = 0; kt < Nn / 64; ++kt) {
        const int koff = kt * 64;

        // ---- issue all loads for this tile up front (no barriers anywhere) ----
        bf16x8 vf[2][4];
        #pragma unroll
        for (int kk = 0; kk < 2; ++kk)
            #pragma unroll
            for (int nb = 0; nb < 4; ++nb)
                vf[kk][nb] = *(const bf16x8*)(vptr + (size_t)nb * 16 * Nn + koff + kk * 32);

        floatx4 bias4[4];
        #pragma unroll
        for (int blk = 0; blk < 4; ++blk)
            bias4[blk] = *(const floatx4*)(bptr + koff + blk * 16);

        floatx4 madd[4];
        if (mask_i32) {
            #pragma unroll
            for (int blk = 0; blk < 4; ++blk) {
                int4 t = *(const int4*)(mip + koff + blk * 16);
                floatx4 f;
                f[0] = t.x ? 0.f : NEGF; f[1] = t.y ? 0.f : NEGF;
                f[2] = t.z ? 0.f : NEGF; f[3] = t.w ? 0.f : NEGF;
                madd[blk] = f;
            }
        } else {
            #pragma unroll
            for (int blk = 0; blk < 4; ++blk) {
                uint32_t t = *(const uint32_t*)(mbp + koff + blk * 16);
                floatx4 f;
                f[0] = (t & 0xffu)       ? 0.f : NEGF;
                f[1] = (t & 0xff00u)     ? 0.f : NEGF;
                f[2] = (t & 0xff0000u)   ? 0.f : NEGF;
                f[3] = (t & 0xff000000u) ? 0.f : NEGF;
                madd[blk] = f;
            }
        }

        // ---- S^T = K * Q^T : 64 keys (regs) x 16 queries (lanes) ----
        floatx4 sacc[4];
        #pragma unroll
        for (int blk = 0; blk < 4; ++blk) {
            const bf16_t* kr = kptr + (size_t)(koff + blk * 16) * Dd;
            bf16x8 ka = *(const bf16x8*)(kr);
            bf16x8 kc = *(const bf16x8*)(kr + 32);
            floatx4 acc = (floatx4){0.f, 0.f, 0.f, 0.f};
            acc = __builtin_amdgcn_mfma_f32_16x16x32_bf16(ka, qf[0], acc, 0, 0, 0);
            acc = __builtin_amdgcn_mfma_f32_16x16x32_bf16(kc, qf[1], acc, 0, 0, 0);
            sacc[blk] = acc;
        }

        // ---- scale + bias + mask; online softmax (per-lane scalar state) ----
        float sv[16];
        float rmax = NEGF;
        #pragma unroll
        for (int blk = 0; blk < 4; ++blk)
            #pragma unroll
            for (int r = 0; r < 4; ++r) {
                float val = fmaf(sacc[blk][r], SCALE, bias4[blk][r]) + madd[blk][r];
                sv[blk * 4 + r] = val;
                rmax = fmaxf(rmax, val);
            }
        rmax = fmaxf(rmax, __shfl_xor(rmax, 16, 64));
        rmax = fmaxf(rmax, __shfl_xor(rmax, 32, 64));

        const float mnew  = fmaxf(mx, rmax);
        const float alpha = __expf(mx - mnew);
        mx = mnew;

        float rsum = 0.f;
        uint2 pb[4];
        #pragma unroll
        for (int blk = 0; blk < 4; ++blk) {
            bf16x4 p4;
            #pragma unroll
            for (int r = 0; r < 4; ++r) {
                const bf16_t p = (bf16_t)__expf(sv[blk * 4 + r] - mnew);
                p4[r] = p;
                rsum += (float)p;   // sum bf16-rounded p: num/denom consistent
            }
            pb[blk] = __builtin_bit_cast(uint2, p4);
        }
        rsum += __shfl_xor(rsum, 16, 64);
        rsum += __shfl_xor(rsum, 32, 64);
        lsum = lsum * alpha + rsum;
        #pragma unroll
        for (int nb = 0; nb < 4; ++nb)
            o_acc[nb] *= alpha;

        // ---- P: C-layout -> B-layout via butterfly bpermute (no LDS storage) ----
        #pragma unroll
        for (int kk = 0; kk < 2; ++kk) {
            uint2 a0 = bperm64(pb[2 * kk],     lo_src);
            uint2 b0 = bperm64(pb[2 * kk + 1], lo_src);
            uint2 a1 = bperm64(pb[2 * kk],     hi_src);
            uint2 b1 = bperm64(pb[2 * kk + 1], hi_src);
            uint2 lo = hiSel ? b0 : a0;
            uint2 hi = hiSel ? b1 : a1;
            uint4 pw = make_uint4(lo.x, lo.y, hi.x, hi.y);
            bf16x8 pf = __builtin_bit_cast(bf16x8, pw);
            #pragma unroll
            for (int nb = 0; nb < 4; ++nb)
                o_acc[nb] = __builtin_amdgcn_mfma_f32_16x16x32_bf16(
                    vf[kk][nb], pf, o_acc[nb], 0, 0, 0);
        }
    }

    // ---- epilogue: O^T rows d = nb*16 + q*4 + r, col m; float4 stores ----
    const float inv = 1.f / lsum;
    float* op = outg + head + (size_t)m * Dd + q * 4;
    #pragma unroll
    for (int nb = 0; nb < 4; ++nb) {
        float4 o;
        o.x = o_acc[nb][0] * inv; o.y = o_acc[nb][1] * inv;
        o.z = o_acc[nb][2] * inv; o.w = o_acc[nb][3] * inv;
        *(float4*)(op + nb * 16) = o;
    }
}

extern "C" void kernel_launch(void* const* d_in, const int* in_sizes, int n_in,
                              void* d_out, int out_size, void* d_ws, size_t ws_size,
                              hipStream_t stream) {
    const float* q    = (const float*)d_in[0];
    const float* k    = (const float*)d_in[1];
    const float* v    = (const float*)d_in[2];
    const void*  mask = d_in[3];
    const float* bias = (const float*)d_in[4];
    float* out = (float*)d_out;
    (void)in_sizes; (void)n_in; (void)out_size; (void)ws_size;

    bf16_t* kbf = (bf16_t*)d_ws;            // 16.8 MB
    bf16_t* vtb = kbf + KELEMS;             // 16.8 MB

    cvt_k<<<(int)(KELEMS / (256 * 8)), 256, 0, stream>>>(k, kbf);
    transpose_v<<<Bb * Hh * (Nn / 64), 256, 0, stream>>>(v, vtb);
    attn_fwd<<<Bb * Hh * (Nn / 64), 256, 0, stream>>>(q, kbf, vtb, mask, bias, out);
}